// Round 5
// baseline (359.703 us; speedup 1.0000x reference)
//
#include <hip/hip_runtime.h>
#include <hip/hip_cooperative_groups.h>

namespace cg = cooperative_groups;

#define D_DIM 1024
#define B_HALF 4096
#define NROWS 8192
#define INV_TEMP 10.0f
#define NTILES 2080   // 64*65/2 upper-triangular 128x128 tiles

typedef __bf16 bf16x8 __attribute__((ext_vector_type(8)));
typedef float floatx4 __attribute__((ext_vector_type(4)));

__device__ __forceinline__ unsigned short f32_to_bf16(float f) {
    union { float f; unsigned u; } v; v.f = f;
    unsigned r = 0x7FFFu + ((v.u >> 16) & 1u);
    return (unsigned short)((v.u + r) >> 16);
}

// One 128x128 tile of sim = R R^T * 10 (BK=32: 64B LDS row stride keeps bank
// conflicts at the free 2-way level -- BK=64's 128B stride tripled them, R3).
// exp row sums + (by symmetry) col sums accumulated into Srow via atomics.
__device__ __forceinline__ void process_tile(
    int t, const unsigned short* __restrict__ R,
    float* __restrict__ Srow, float* __restrict__ pos, int tid)
{
    __shared__ unsigned short As[128 * 32];
    __shared__ unsigned short Bs[128 * 32];
    __shared__ float rowsum[2][128];
    __shared__ float colsum[2][128];

    const int wave = tid >> 6, lane = tid & 63;
    const int wm = wave >> 1, wn = wave & 1;
    const int lrow = lane >> 2;        // staging: row within 16-row chunk
    const int lk = (lane & 3) * 8;     // staging: 16B granule within 32-elem slab
    const int lm = lane & 15;
    const int lq = lane >> 4;

    // decode linear t -> (rt, ct), rt <= ct, rt-major
    int rt = (int)((129.0f - sqrtf((float)(16641 - 8 * t))) * 0.5f);
    while ((rt + 1) * 64 - (rt + 1) * rt / 2 <= t) ++rt;
    while (rt * 64 - rt * (rt - 1) / 2 > t) --rt;
    const int ct = rt + (t - (rt * 64 - rt * (rt - 1) / 2));
    const bool isDiag = (rt == ct);
    const int row0 = rt * 128, col0 = ct * 128;

    const unsigned short* gA = R + (size_t)row0 * D_DIM;
    const unsigned short* gB = R + (size_t)col0 * D_DIM;

    floatx4 acc[4][4] = {};

    for (int k0 = 0; k0 < D_DIM; k0 += 32) {
        #pragma unroll
        for (int rnd = 0; rnd < 2; ++rnd) {
            const int c = rnd * 4 + wave;        // chunk 0..7 (16 rows each)
            const int grow = c * 16 + lrow;
            __builtin_amdgcn_global_load_lds(
                (const __attribute__((address_space(1))) unsigned int*)(gA + (size_t)grow * D_DIM + k0 + lk),
                (__attribute__((address_space(3))) unsigned int*)(As + c * 512),
                16, 0, 0);
            __builtin_amdgcn_global_load_lds(
                (const __attribute__((address_space(1))) unsigned int*)(gB + (size_t)grow * D_DIM + k0 + lk),
                (__attribute__((address_space(3))) unsigned int*)(Bs + c * 512),
                16, 0, 0);
        }
        __syncthreads();

        bf16x8 af[4], bfr[4];
        #pragma unroll
        for (int i = 0; i < 4; ++i) {
            af[i]  = *(const bf16x8*)(As + (wm * 64 + i * 16 + lm) * 32 + lq * 8);
            bfr[i] = *(const bf16x8*)(Bs + (wn * 64 + i * 16 + lm) * 32 + lq * 8);
        }
        #pragma unroll
        for (int mi = 0; mi < 4; ++mi)
            #pragma unroll
            for (int ni = 0; ni < 4; ++ni)
                acc[mi][ni] = __builtin_amdgcn_mfma_f32_16x16x32_bf16(
                    af[mi], bfr[ni], acc[mi][ni], 0, 0, 0);
        __syncthreads();
    }

    // Epilogue: exp once per element; row sums and (by symmetry) col sums.
    float ecol[4] = {0.0f, 0.0f, 0.0f, 0.0f};
    #pragma unroll
    for (int mi = 0; mi < 4; ++mi) {
        #pragma unroll
        for (int reg = 0; reg < 4; ++reg) {
            const int gr = row0 + wm * 64 + mi * 16 + lq * 4 + reg;
            float esum = 0.0f;
            #pragma unroll
            for (int ni = 0; ni < 4; ++ni) {
                const int gc = col0 + wn * 64 + ni * 16 + lm;
                float s = acc[mi][ni][reg] * INV_TEMP;
                if (gc == gr + B_HALF) { pos[gr] = s; pos[gc] = s; }
                float e = (gc == gr) ? 0.0f : __expf(s);
                esum += e;
                ecol[ni] += e;
            }
            esum += __shfl_xor(esum, 1);
            esum += __shfl_xor(esum, 2);
            esum += __shfl_xor(esum, 4);
            esum += __shfl_xor(esum, 8);
            if (lm == 0) rowsum[wn][wm * 64 + mi * 16 + lq * 4 + reg] = esum;
        }
    }
    #pragma unroll
    for (int ni = 0; ni < 4; ++ni) {
        ecol[ni] += __shfl_xor(ecol[ni], 16);
        ecol[ni] += __shfl_xor(ecol[ni], 32);
    }
    if (lq == 0 && !isDiag) {
        #pragma unroll
        for (int ni = 0; ni < 4; ++ni)
            colsum[wm][wn * 64 + ni * 16 + lm] = ecol[ni];
    }
    __syncthreads();
    if (tid < 128) {
        unsafeAtomicAdd(&Srow[row0 + tid], rowsum[0][tid] + rowsum[1][tid]);
        if (!isDiag)
            unsafeAtomicAdd(&Srow[col0 + tid], colsum[0][tid] + colsum[1][tid]);
    }
    __syncthreads();   // shared reads done before any next-tile reuse
}

// ---------------- Cooperative fused kernel ----------------
__global__ __launch_bounds__(256) void fused_kernel(
    const float* __restrict__ z1, const float* __restrict__ z2,
    unsigned short* __restrict__ R, float* __restrict__ Srow,
    float* __restrict__ pos, unsigned int* __restrict__ ctr,
    float* __restrict__ out)
{
    __shared__ float red[4];
    __shared__ int s_t;
    const int tid = threadIdx.x;
    const int bid = blockIdx.x;
    const int nb = gridDim.x;
    const int wave = tid >> 6, lane = tid & 63;

    // Phase A: normalize rows -> bf16 R; zero Srow; reset tile counter.
    if (bid == 0 && tid == 0) ctr[0] = 0u;
    for (int row = bid; row < NROWS; row += nb) {
        const float* src = (row < B_HALF) ? (z1 + (size_t)row * D_DIM)
                                          : (z2 + (size_t)(row - B_HALF) * D_DIM);
        float4 v = ((const float4*)src)[tid];
        float ss = v.x * v.x + v.y * v.y + v.z * v.z + v.w * v.w;
        #pragma unroll
        for (int off = 32; off > 0; off >>= 1) ss += __shfl_down(ss, off);
        if (lane == 0) red[wave] = ss;
        __syncthreads();
        float tot = red[0] + red[1] + red[2] + red[3];
        float scale = 1.0f / fmaxf(sqrtf(tot), 1e-12f);
        ushort4 o;
        o.x = f32_to_bf16(v.x * scale);
        o.y = f32_to_bf16(v.y * scale);
        o.z = f32_to_bf16(v.z * scale);
        o.w = f32_to_bf16(v.w * scale);
        ((ushort4*)(R + (size_t)row * D_DIM))[tid] = o;
        if (tid == 0) Srow[row] = 0.0f;
        __syncthreads();   // red[] reuse in next iteration
    }
    cg::this_grid().sync();

    // Phase B: dynamic tile stealing -- perfectly balanced regardless of grid.
    for (;;) {
        if (tid == 0) s_t = (int)atomicAdd(ctr, 1u);
        __syncthreads();
        const int t = s_t;
        if (t >= NTILES) break;
        process_tile(t, R, Srow, pos, tid);   // ends with __syncthreads()
    }
    cg::this_grid().sync();

    // Phase C: block 0 reduces -> loss.
    if (bid == 0) {
        float c = 0.0f;
        for (int r = tid; r < NROWS; r += 256)
            c += log1pf(Srow[r] * __expf(-pos[r]));
        #pragma unroll
        for (int off = 32; off > 0; off >>= 1) c += __shfl_down(c, off);
        __syncthreads();
        if (lane == 0) red[wave] = c;
        __syncthreads();
        if (tid == 0)
            out[0] = (red[0] + red[1] + red[2] + red[3]) * (1.0f / 8192.0f);
    }
}

// ---------------- Fallback path (classic 3-kernel, proven R2 body) ----------
__global__ __launch_bounds__(256) void normalize_kernel(
    const float* __restrict__ z1, const float* __restrict__ z2,
    unsigned short* __restrict__ R, float* __restrict__ Srow,
    float* __restrict__ out)
{
    const int row = blockIdx.x;
    const int tid = threadIdx.x;
    if (row == 0 && tid == 0) out[0] = 0.0f;
    const float* src = (row < B_HALF) ? (z1 + (size_t)row * D_DIM)
                                      : (z2 + (size_t)(row - B_HALF) * D_DIM);
    float4 v = ((const float4*)src)[tid];
    float ss = v.x * v.x + v.y * v.y + v.z * v.z + v.w * v.w;
    #pragma unroll
    for (int off = 32; off > 0; off >>= 1) ss += __shfl_down(ss, off);
    __shared__ float wsum[4];
    if ((tid & 63) == 0) wsum[tid >> 6] = ss;
    __syncthreads();
    float tot = wsum[0] + wsum[1] + wsum[2] + wsum[3];
    float scale = 1.0f / fmaxf(sqrtf(tot), 1e-12f);
    ushort4 o;
    o.x = f32_to_bf16(v.x * scale);
    o.y = f32_to_bf16(v.y * scale);
    o.z = f32_to_bf16(v.z * scale);
    o.w = f32_to_bf16(v.w * scale);
    ((ushort4*)(R + (size_t)row * D_DIM))[tid] = o;
    if (tid == 0) Srow[row] = 0.0f;
}

__global__ __launch_bounds__(256) void gemm_kernel(
    const unsigned short* __restrict__ R,
    float* __restrict__ Srow, float* __restrict__ pos)
{
    process_tile(blockIdx.x, R, Srow, pos, threadIdx.x);
}

__global__ __launch_bounds__(256) void finalize_kernel(
    const float* __restrict__ Srow, const float* __restrict__ pos,
    float* __restrict__ out)
{
    const int r = blockIdx.x * 256 + threadIdx.x;
    float c = log1pf(Srow[r] * __expf(-pos[r]));
    #pragma unroll
    for (int off = 32; off > 0; off >>= 1) c += __shfl_down(c, off);
    __shared__ float wsum[4];
    if ((threadIdx.x & 63) == 0) wsum[threadIdx.x >> 6] = c;
    __syncthreads();
    if (threadIdx.x == 0)
        atomicAdd(out, (wsum[0] + wsum[1] + wsum[2] + wsum[3]) * (1.0f / 8192.0f));
}

extern "C" void kernel_launch(void* const* d_in, const int* in_sizes, int n_in,
                              void* d_out, int out_size, void* d_ws, size_t ws_size,
                              hipStream_t stream)
{
    const float* z1 = (const float*)d_in[0];
    const float* z2 = (const float*)d_in[1];
    float* out = (float*)d_out;
    char* ws = (char*)d_ws;
    unsigned short* R = (unsigned short*)ws;                        // 16 MiB bf16 reps
    float* Srow = (float*)(ws + (size_t)16 * 1024 * 1024);          // 32 KiB [8192]
    float* pos  = (float*)(ws + (size_t)16 * 1024 * 1024 + 32768);  // 32 KiB [8192]
    unsigned int* ctr = (unsigned int*)(ws + (size_t)16 * 1024 * 1024 + 65536);

    // Size the cooperative grid from the runtime's own occupancy model so the
    // co-residency validation cannot reject it (R4: hand-computed 1040 was
    // rejected -> kernel never ran).
    int nPerCU = 0;
    hipError_t oe = hipOccupancyMaxActiveBlocksPerMultiprocessor(
        &nPerCU, fused_kernel, 256, 0);
    int grid = (oe == hipSuccess && nPerCU > 0) ? nPerCU * 256 : 0;
    if (grid > NTILES) grid = NTILES;

    hipError_t e = hipErrorUnknown;
    if (grid >= 256) {
        void* args[] = { (void*)&z1, (void*)&z2, (void*)&R, (void*)&Srow,
                         (void*)&pos, (void*)&ctr, (void*)&out };
        e = hipLaunchCooperativeKernel((const void*)fused_kernel,
                                       dim3(grid), dim3(256), args, 0, stream);
    }
    if (e != hipSuccess) {
        // Deterministic fallback: proven classic pipeline.
        normalize_kernel<<<NROWS, 256, 0, stream>>>(z1, z2, R, Srow, out);
        gemm_kernel<<<NTILES, 256, 0, stream>>>(R, Srow, pos);
        finalize_kernel<<<32, 256, 0, stream>>>(Srow, pos, out);
    }
}

// Round 6
// 215.194 us; speedup vs baseline: 1.6715x; 1.6715x over previous
//
#include <hip/hip_runtime.h>

#define D_DIM 1024
#define B_HALF 4096
#define NROWS 8192
#define INV_TEMP 10.0f
#define NTILES 2080   // 64*65/2 upper-triangular 128x128 tiles

typedef float floatx4 __attribute__((ext_vector_type(4)));
typedef int i32x4 __attribute__((ext_vector_type(4)));
typedef int i32x8 __attribute__((ext_vector_type(8)));

// Kernel 1: L2-normalize rows of z1,z2 -> fp8 e4m3 (OCP, native on gfx950)
// R [8192][1024] bytes. Also zero-inits Srow and out.
__global__ __launch_bounds__(256) void normalize_kernel(
    const float* __restrict__ z1, const float* __restrict__ z2,
    unsigned char* __restrict__ R, float* __restrict__ Srow,
    float* __restrict__ out)
{
    const int row = blockIdx.x;
    const int tid = threadIdx.x;
    if (row == 0 && tid == 0) out[0] = 0.0f;
    const float* src = (row < B_HALF) ? (z1 + (size_t)row * D_DIM)
                                      : (z2 + (size_t)(row - B_HALF) * D_DIM);
    float4 v = ((const float4*)src)[tid];
    float ss = v.x * v.x + v.y * v.y + v.z * v.z + v.w * v.w;
    #pragma unroll
    for (int off = 32; off > 0; off >>= 1) ss += __shfl_down(ss, off);
    __shared__ float wsum[4];
    if ((tid & 63) == 0) wsum[tid >> 6] = ss;
    __syncthreads();
    float tot = wsum[0] + wsum[1] + wsum[2] + wsum[3];
    float scale = 1.0f / fmaxf(sqrtf(tot), 1e-12f);
    // pack 4 fp8 bytes: elements (x,y,z,w) -> bytes (0,1,2,3)
    int w = __builtin_amdgcn_cvt_pk_fp8_f32(v.x * scale, v.y * scale, 0, false);
    w = __builtin_amdgcn_cvt_pk_fp8_f32(v.z * scale, v.w * scale, w, true);
    ((int*)(R + (size_t)row * D_DIM))[tid] = w;
    if (tid == 0) Srow[row] = 0.0f;
}

// Kernel 2: one upper-tri 128x128 tile of sim = (R R^T)*10 via MX-fp8
// mfma_scale 16x16x128 (scales pinned to 1.0 -> exact fp8 GEMM).
// Fragment-major LDS: chunk c (1 KB) holds lane*16 granules so BOTH the
// global_load_lds staging and the ds_read_b128 fragment reads are sequential
// 1 KB bursts -- no 128B-stride bank conflicts (R3 lesson).
__global__ __launch_bounds__(256) void gemm_kernel(
    const unsigned char* __restrict__ R,
    float* __restrict__ Srow, float* __restrict__ pos)
{
    __shared__ __align__(16) unsigned char As[16384];
    __shared__ __align__(16) unsigned char Bs[16384];
    __shared__ float rowsum[2][128];
    __shared__ float colsum[2][128];

    // decode linear blockIdx -> (rt, ct), rt <= ct, rt-major
    const int t = blockIdx.x;
    int rt = (int)((129.0f - sqrtf((float)(16641 - 8 * t))) * 0.5f);
    while ((rt + 1) * 64 - (rt + 1) * rt / 2 <= t) ++rt;
    while (rt * 64 - rt * (rt - 1) / 2 > t) --rt;
    const int ct = rt + (t - (rt * 64 - rt * (rt - 1) / 2));
    const bool isDiag = (rt == ct);
    const int row0 = rt * 128, col0 = ct * 128;

    const int tid = threadIdx.x;
    const int wave = tid >> 6, lane = tid & 63;
    const int wm = wave >> 1, wn = wave & 1;
    const int lm = lane & 15;
    const int lq = lane >> 4;

    const unsigned char* gA = R + (size_t)row0 * D_DIM;
    const unsigned char* gB = R + (size_t)col0 * D_DIM;

    // staging per-lane global-gather pieces: chunk (mc,g) slot `lane` holds
    // row mc*16+(lane&15), k-bytes kgrp + g*16 .. +15
    const int srow = lane & 15;
    const int kgrp = (lane >> 4) * 32;

    floatx4 acc[4][4] = {};

    for (int k0 = 0; k0 < D_DIM; k0 += 128) {
        #pragma unroll
        for (int h = 0; h < 8; ++h) {
            const int c = h * 4 + wave;          // 0..31: 16 A-chunks, 16 B-chunks
            const int cc = c & 15;
            const int mc = cc >> 1, g = cc & 1;
            const unsigned char* gsrc = ((c < 16) ? gA : gB)
                + (size_t)(mc * 16 + srow) * D_DIM + k0 + kgrp + g * 16;
            unsigned char* ldst = ((c < 16) ? As : Bs) + (cc << 10);
            __builtin_amdgcn_global_load_lds(
                (const __attribute__((address_space(1))) unsigned int*)gsrc,
                (__attribute__((address_space(3))) unsigned int*)ldst,
                16, 0, 0);
        }
        __syncthreads();

        i32x8 af[4], bfr[4];
        #pragma unroll
        for (int i = 0; i < 4; ++i) {
            union { i32x8 v8; struct { i32x4 lo, hi; } p; } ua, ub;
            const int ca = (wm * 4 + i) * 2;
            ua.p.lo = *(const i32x4*)(As + (ca << 10) + lane * 16);
            ua.p.hi = *(const i32x4*)(As + ((ca + 1) << 10) + lane * 16);
            af[i] = ua.v8;
            const int cb = (wn * 4 + i) * 2;
            ub.p.lo = *(const i32x4*)(Bs + (cb << 10) + lane * 16);
            ub.p.hi = *(const i32x4*)(Bs + ((cb + 1) << 10) + lane * 16);
            bfr[i] = ub.v8;
        }
        #pragma unroll
        for (int mi = 0; mi < 4; ++mi)
            #pragma unroll
            for (int ni = 0; ni < 4; ++ni)
                acc[mi][ni] = __builtin_amdgcn_mfma_scale_f32_16x16x128_f8f6f4(
                    af[mi], bfr[ni], acc[mi][ni],
                    0, 0,                    // cbsz=fp8(e4m3), blgp=fp8(e4m3)
                    0, 0x7F7F7F7F,           // A scales: E8M0 127 = 1.0
                    0, 0x7F7F7F7F);          // B scales: 1.0
        __syncthreads();
    }

    // Epilogue (C/D layout of 16x16 is shape-determined, same as bf16):
    // exp once per element; row sums and (by symmetry) col sums.
    float ecol[4] = {0.0f, 0.0f, 0.0f, 0.0f};
    #pragma unroll
    for (int mi = 0; mi < 4; ++mi) {
        #pragma unroll
        for (int reg = 0; reg < 4; ++reg) {
            const int gr = row0 + wm * 64 + mi * 16 + lq * 4 + reg;
            float esum = 0.0f;
            #pragma unroll
            for (int ni = 0; ni < 4; ++ni) {
                const int gc = col0 + wn * 64 + ni * 16 + lm;
                float s = acc[mi][ni][reg] * INV_TEMP;
                if (gc == gr + B_HALF) { pos[gr] = s; pos[gc] = s; }
                float e = (gc == gr) ? 0.0f : __expf(s);
                esum += e;
                ecol[ni] += e;
            }
            esum += __shfl_xor(esum, 1);
            esum += __shfl_xor(esum, 2);
            esum += __shfl_xor(esum, 4);
            esum += __shfl_xor(esum, 8);
            if (lm == 0) rowsum[wn][wm * 64 + mi * 16 + lq * 4 + reg] = esum;
        }
    }
    #pragma unroll
    for (int ni = 0; ni < 4; ++ni) {
        ecol[ni] += __shfl_xor(ecol[ni], 16);
        ecol[ni] += __shfl_xor(ecol[ni], 32);
    }
    if (lq == 0 && !isDiag) {
        #pragma unroll
        for (int ni = 0; ni < 4; ++ni)
            colsum[wm][wn * 64 + ni * 16 + lm] = ecol[ni];
    }
    __syncthreads();
    if (tid < 128) {
        unsafeAtomicAdd(&Srow[row0 + tid], rowsum[0][tid] + rowsum[1][tid]);
        if (!isDiag)
            unsafeAtomicAdd(&Srow[col0 + tid], colsum[0][tid] + colsum[1][tid]);
    }
}

// Kernel 3: loss = mean(log1p(Srow * exp(-pos)))
__global__ __launch_bounds__(256) void finalize_kernel(
    const float* __restrict__ Srow, const float* __restrict__ pos,
    float* __restrict__ out)
{
    const int r = blockIdx.x * 256 + threadIdx.x;
    float c = log1pf(Srow[r] * __expf(-pos[r]));
    #pragma unroll
    for (int off = 32; off > 0; off >>= 1) c += __shfl_down(c, off);
    __shared__ float wsum[4];
    if ((threadIdx.x & 63) == 0) wsum[threadIdx.x >> 6] = c;
    __syncthreads();
    if (threadIdx.x == 0)
        atomicAdd(out, (wsum[0] + wsum[1] + wsum[2] + wsum[3]) * (1.0f / 8192.0f));
}

extern "C" void kernel_launch(void* const* d_in, const int* in_sizes, int n_in,
                              void* d_out, int out_size, void* d_ws, size_t ws_size,
                              hipStream_t stream)
{
    const float* z1 = (const float*)d_in[0];
    const float* z2 = (const float*)d_in[1];
    float* out = (float*)d_out;
    char* ws = (char*)d_ws;
    unsigned char* R = (unsigned char*)ws;                          // 8 MiB fp8 reps
    float* Srow = (float*)(ws + (size_t)8 * 1024 * 1024);           // 32 KiB [8192]
    float* pos  = (float*)(ws + (size_t)8 * 1024 * 1024 + 32768);   // 32 KiB [8192]

    normalize_kernel<<<NROWS, 256, 0, stream>>>(z1, z2, R, Srow, out);
    gemm_kernel<<<NTILES, 256, 0, stream>>>(R, Srow, pos);
    finalize_kernel<<<32, 256, 0, stream>>>(Srow, pos, out);
}